// Round 2
// baseline (269.866 us; speedup 1.0000x reference)
//
#include <hip/hip_runtime.h>

#define NATOMS 2048
#define R_DIM 512
#define P_DIM 256
#define S_DIM 4
#define NSTACKS 32
#define F_DIM 8192
#define KS 8                 // K splits
#define KSPAN (R_DIM / KS)   // 64
#define TR 64                // rows per tile
#define TC 64                // cols per tile
#define KT 16                // k chunk
#define ROW_TILES (NATOMS / TR)  // 32 (worst case one s owns all atoms)

// ws layout:
//   [0, 8192)        : order  (int[2048])
//   [8192, 8224)     : meta   (gstart[4], gcount[4])
//   [16384, +16MB)   : proj partials  float[KS][2048][256]

__global__ __launch_bounds__(256) void sorf_sort_kernel(
    const int* __restrict__ charges, int* __restrict__ order, int* __restrict__ meta,
    float* __restrict__ out) {
  __shared__ int cnt[S_DIM];
  __shared__ int base[S_DIM];
  int t = threadIdx.x;
  if (t < 32) out[t] = 0.f;   // d_out is re-poisoned before every launch
  if (t < S_DIM) cnt[t] = 0;
  __syncthreads();
  for (int i = t; i < NATOMS; i += 256) atomicAdd(&cnt[charges[i]], 1);
  __syncthreads();
  if (t == 0) {
    int run = 0;
    for (int s = 0; s < S_DIM; ++s) {
      base[s] = run; meta[s] = run; meta[4 + s] = cnt[s]; run += cnt[s];
    }
  }
  __syncthreads();
  for (int i = t; i < NATOMS; i += 256) {
    int s = charges[i];
    int pos = atomicAdd(&base[s], 1);
    order[pos] = i;
  }
}

// grid: bid -> ks(8) | cb(4) | rt(32) | s(4)  = 4096 blocks, 256 threads.
// ~3/4 of row-tiles are empty for a given s and return immediately.
__global__ __launch_bounds__(256) void sorf_proj_kernel(
    const float* __restrict__ rep, const float* __restrict__ reductors,
    const int* __restrict__ order, const int* __restrict__ meta,
    float* __restrict__ projp) {
  int bid = blockIdx.x;
  int ks = bid & 7;
  int cb = (bid >> 3) & 3;
  int rt = (bid >> 5) & 31;
  int s  = bid >> 10;
  int cnt = meta[4 + s];
  if (rt * TR >= cnt) return;
  int start = meta[s] + rt * TR;
  int nrows = min(TR, cnt - rt * TR);

  __shared__ int rows[TR];
  __shared__ float As[KT][TR + 4];  // stride 68 floats = 272B: 16B-aligned rows, 2-way-max bank aliasing
  __shared__ float Bs[KT][TC];

  int t = threadIdx.x;
  if (t < TR) rows[t] = order[start + min(t, nrows - 1)];
  __syncthreads();

  int ar = t >> 2;       // A row this thread stages (0..63)
  int aq = t & 3;        // which k-quad of the KT chunk
  const float* aSrc = rep + (size_t)rows[ar] * R_DIM + ks * KSPAN + aq * 4;
  int kb = t >> 4;       // B k row (0..15)
  int cc = (t & 15) * 4; // B col quad
  const float* bSrc = reductors + ((size_t)s * R_DIM + ks * KSPAN + kb) * P_DIM + cb * TC + cc;

  int ty = t >> 4, tx = t & 15;
  int r0 = ty * 4, c0 = tx * 4;

  float acc[4][4];
#pragma unroll
  for (int i = 0; i < 4; ++i)
#pragma unroll
    for (int j = 0; j < 4; ++j) acc[i][j] = 0.f;

#pragma unroll
  for (int k0 = 0; k0 < KSPAN; k0 += KT) {
    float4 a = *(const float4*)(aSrc + k0);
    float4 b = *(const float4*)(bSrc + (size_t)k0 * P_DIM);
    __syncthreads();   // previous iteration's LDS reads complete
    As[aq * 4 + 0][ar] = a.x;
    As[aq * 4 + 1][ar] = a.y;
    As[aq * 4 + 2][ar] = a.z;
    As[aq * 4 + 3][ar] = a.w;
    *(float4*)&Bs[kb][cc] = b;
    __syncthreads();
#pragma unroll
    for (int kk = 0; kk < KT; ++kk) {
      float4 aV = *(const float4*)&As[kk][r0];
      float4 bV = *(const float4*)&Bs[kk][c0];
      float av[4] = {aV.x, aV.y, aV.z, aV.w};
      float bv[4] = {bV.x, bV.y, bV.z, bV.w};
#pragma unroll
      for (int i = 0; i < 4; ++i)
#pragma unroll
        for (int j = 0; j < 4; ++j) acc[i][j] = fmaf(av[i], bv[j], acc[i][j]);
    }
  }

#pragma unroll
  for (int i = 0; i < 4; ++i) {
    int r = r0 + i;
    if (r < nrows) {
      float* dst = projp + ((size_t)ks * NATOMS + rows[r]) * P_DIM + cb * TC + c0;
      *(float4*)dst = make_float4(acc[i][0], acc[i][1], acc[i][2], acc[i][3]);
    }
  }
}

__global__ __launch_bounds__(256) void sorf_feat_kernel(
    const float* __restrict__ projp, const int* __restrict__ charges,
    const float* __restrict__ Dmat, const float* __restrict__ bias,
    const float* __restrict__ alpha, float* __restrict__ out) {
  const int atom = blockIdx.x;
  const int t = threadIdx.x;
  const int lane = t & 63;
  const int wave = t >> 6;
  const int s = charges[atom];

  // lane holds elements p = 4*lane + k, k=0..3; sum the KS K-split partials
  float4 p = *((const float4*)(projp + (size_t)atom * P_DIM) + lane);
#pragma unroll
  for (int ks = 1; ks < KS; ++ks) {
    float4 q = *((const float4*)(projp + ((size_t)ks * NATOMS + atom) * P_DIM) + lane);
    p.x += q.x; p.y += q.y; p.z += q.z; p.w += q.w;
  }

  const float* Db = Dmat + (size_t)s * (NSTACKS * P_DIM);
  const float* bb = bias + (size_t)s * F_DIM;
  float accum = 0.f;

  for (int j = wave * 8; j < wave * 8 + 8; ++j) {
    float4 d  = *((const float4*)(Db + j * P_DIM) + lane);
    float4 bi = *((const float4*)(bb + j * P_DIM) + lane);
    float4 al = *((const float4*)(alpha + j * P_DIM) + lane);
    float x0 = (d.x >= 0.f) ? p.x : -p.x;
    float x1 = (d.y >= 0.f) ? p.y : -p.y;
    float x2 = (d.z >= 0.f) ? p.z : -p.z;
    float x3 = (d.w >= 0.f) ? p.w : -p.w;
    // FWHT bits 0,1 in-register
    float t0 = x0 + x1, t1 = x0 - x1, t2 = x2 + x3, t3 = x2 - x3;
    x0 = t0 + t2; x2 = t0 - t2; x1 = t1 + t3; x3 = t1 - t3;
    // FWHT bits 2..7 via cross-lane butterflies (stages commute)
#pragma unroll
    for (int hl = 1; hl <= 32; hl <<= 1) {
      float sg = (lane & hl) ? -1.f : 1.f;
      float y0 = __shfl_xor(x0, hl);
      float y1 = __shfl_xor(x1, hl);
      float y2 = __shfl_xor(x2, hl);
      float y3 = __shfl_xor(x3, hl);
      x0 = fmaf(sg, x0, y0);
      x1 = fmaf(sg, x1, y1);
      x2 = fmaf(sg, x2, y2);
      x3 = fmaf(sg, x3, y3);
    }
    // scale 1/16 (fwht norm); COEFF_NORM = 1.0 exactly
    accum += __cosf(fmaf(x0, 0.0625f, bi.x)) * al.x;
    accum += __cosf(fmaf(x1, 0.0625f, bi.y)) * al.y;
    accum += __cosf(fmaf(x2, 0.0625f, bi.z)) * al.z;
    accum += __cosf(fmaf(x3, 0.0625f, bi.w)) * al.w;
  }

#pragma unroll
  for (int off = 1; off < 64; off <<= 1) accum += __shfl_xor(accum, off);
  __shared__ float wsum[4];
  if (lane == 0) wsum[wave] = accum;
  __syncthreads();
  if (t == 0) {
    // FEAT_NORM = sqrt(2/8192) = 1/64 exactly
    atomicAdd(out + (atom >> 6), 0.015625f * ((wsum[0] + wsum[1]) + (wsum[2] + wsum[3])));
  }
}

extern "C" void kernel_launch(void* const* d_in, const int* in_sizes, int n_in,
                              void* d_out, int out_size, void* d_ws, size_t ws_size,
                              hipStream_t stream) {
  const float* rep       = (const float*)d_in[0];
  const int*   charges   = (const int*)d_in[1];
  const float* reductors = (const float*)d_in[2];
  const float* Dmat      = (const float*)d_in[3];
  const float* bias      = (const float*)d_in[4];
  const float* alpha     = (const float*)d_in[5];
  float* out = (float*)d_out;

  char* ws = (char*)d_ws;
  int*   order = (int*)ws;
  int*   meta  = (int*)(ws + 8192);
  float* projp = (float*)(ws + 16384);

  sorf_sort_kernel<<<1, 256, 0, stream>>>(charges, order, meta, out);
  sorf_proj_kernel<<<KS * 4 * ROW_TILES * S_DIM, 256, 0, stream>>>(rep, reductors, order, meta, projp);
  sorf_feat_kernel<<<NATOMS, 256, 0, stream>>>(projp, charges, Dmat, bias, alpha, out);
}

// Round 3
// 131.844 us; speedup vs baseline: 2.0469x; 2.0469x over previous
//
#include <hip/hip_runtime.h>

#define NATOMS 2048
#define R_DIM 512
#define P_DIM 256
#define S_DIM 4
#define NSTACKS 32
#define F_DIM 8192
#define TA 8                       // atoms per block
#define NG 4                       // K-split groups within block
#define KC 8                       // k rows per chunk per group
#define NITER (R_DIM / (NG * KC))  // 16

// ws layout: order int[2048] @0 ; meta int[8] @8192 ; sgn u32[4*32*64] @16384 (32KB)

__global__ __launch_bounds__(256) void sorf_prep_kernel(
    const int* __restrict__ charges, const float* __restrict__ Dmat,
    int* __restrict__ order, int* __restrict__ meta, unsigned* __restrict__ sgn,
    float* __restrict__ out) {
  __shared__ int cnt[S_DIM];
  __shared__ int base[S_DIM];
  int t = threadIdx.x;
  if (t < 32) out[t] = 0.f;          // d_out re-poisoned before every launch
  if (t < S_DIM) cnt[t] = 0;
  __syncthreads();
  for (int i = t; i < NATOMS; i += 256) atomicAdd(&cnt[charges[i]], 1);
  __syncthreads();
  if (t == 0) {
    int run = 0;
    for (int s = 0; s < S_DIM; ++s) {
      base[s] = run; meta[s] = run; meta[4 + s] = cnt[s]; run += cnt[s];
    }
  }
  __syncthreads();
  for (int i = t; i < NATOMS; i += 256) {
    int s = charges[i];
    order[atomicAdd(&base[s], 1)] = i;
  }
  // pack D signs: word w <-> float4 index w of Dmat (s*2048 + j*64 + lane)
  for (int w = t; w < S_DIM * NSTACKS * 64; w += 256) {
    float4 d = *((const float4*)Dmat + w);
    unsigned m = (d.x < 0.f ? 1u : 0u) | (d.y < 0.f ? 2u : 0u) |
                 (d.z < 0.f ? 4u : 0u) | (d.w < 0.f ? 8u : 0u);
    sgn[w] = m;
  }
}

// grid: 4 s-groups x 256 row tiles (most empty-return). 512 threads = 8 waves.
__global__ __launch_bounds__(512, 2) void sorf_fused_kernel(
    const float* __restrict__ rep, const float* __restrict__ reductors,
    const float* __restrict__ bias, const float* __restrict__ alpha,
    const int* __restrict__ order, const int* __restrict__ meta,
    const unsigned* __restrict__ sgnw, float* __restrict__ out) {
  int rt = blockIdx.x & 255;
  int s  = blockIdx.x >> 8;
  int cnt = meta[4 + s];
  if (rt * TA >= cnt) return;
  int start = meta[s] + rt * TA;
  int nrows = min(TA, cnt - rt * TA);

  __shared__ float AsP[R_DIM * TA];        // 16 KB: As[k][a]; later proj[8][256] (8 KB overlay)
  __shared__ float BsP[NG * KC * P_DIM];   // 32 KB: Bs[g][kk][p]; later part[g][a][p] overlay
  __shared__ unsigned sgnL[NSTACKS * 64];  // 8 KB
  __shared__ int rows[TA];

  int t = threadIdx.x;
  if (t < TA) rows[t] = order[start + min(t, nrows - 1)];
  for (int i = t; i < NSTACKS * 64; i += 512) sgnL[i] = sgnw[s * (NSTACKS * 64) + i];
  __syncthreads();  // rows visible

  // stage A transposed: As[k][a] (one-time; 8-way write aliasing acceptable)
  for (int f = t; f < 1024; f += 512) {
    int a = f & 7, kq = f >> 3;
    float4 v = *((const float4*)(rep + (size_t)rows[a] * R_DIM) + kq);
    AsP[(kq * 4 + 0) * TA + a] = v.x;
    AsP[(kq * 4 + 1) * TA + a] = v.y;
    AsP[(kq * 4 + 2) * TA + a] = v.z;
    AsP[(kq * 4 + 3) * TA + a] = v.w;
  }

  int g  = t >> 7;        // K-split group 0..3, covers k in [g*128, g*128+128)
  int u  = t & 127;
  int ah = u >> 6;        // atom half: atoms ah*4 .. ah*4+3
  int pq = u & 63;        // p quad: p = pq*4
  const float* Bbase = reductors + (size_t)s * R_DIM * P_DIM;

  float acc[4][4];
#pragma unroll
  for (int i = 0; i < 4; ++i)
#pragma unroll
    for (int j = 0; j < 4; ++j) acc[i][j] = 0.f;

  for (int it = 0; it < NITER; ++it) {
    __syncthreads();  // (first iter: As staged; later: previous compute reads done)
#pragma unroll
    for (int r = 0; r < 4; ++r) {
      int q = t + 512 * r;          // 2048 float4 of B chunk-set
      int gg  = q >> 9;
      int rem = q & 511;
      int kk  = rem >> 6;
      int pq2 = rem & 63;
      int k = gg * 128 + it * KC + kk;
      float4 b = *((const float4*)(Bbase + (size_t)k * P_DIM) + pq2);
      *((float4*)BsP + (gg * KC + kk) * 64 + pq2) = b;
    }
    __syncthreads();
#pragma unroll
    for (int kk = 0; kk < KC; ++kk) {
      int k = g * 128 + it * KC + kk;
      float4 b4 = *((const float4*)BsP + (g * KC + kk) * 64 + pq);
      float4 a4 = *((const float4*)AsP + k * 2 + ah);  // broadcast within wave
      float bv[4] = {b4.x, b4.y, b4.z, b4.w};
      float av[4] = {a4.x, a4.y, a4.z, a4.w};
#pragma unroll
      for (int i = 0; i < 4; ++i)
#pragma unroll
        for (int j = 0; j < 4; ++j) acc[i][j] = fmaf(av[i], bv[j], acc[i][j]);
    }
  }
  __syncthreads();

  // write K-split partials into BsP region: part[g][a][p]
#pragma unroll
  for (int i = 0; i < 4; ++i) {
    int a = ah * 4 + i;
    *((float4*)BsP + (g * TA + a) * 64 + pq) =
        make_float4(acc[i][0], acc[i][1], acc[i][2], acc[i][3]);
  }
  __syncthreads();

  // reduce 4 partials -> proj[a][p] in AsP overlay
  {
    int a = t >> 6, pqq = t & 63;
    float4 r0 = *((const float4*)BsP + (0 * TA + a) * 64 + pqq);
    float4 r1 = *((const float4*)BsP + (1 * TA + a) * 64 + pqq);
    float4 r2 = *((const float4*)BsP + (2 * TA + a) * 64 + pqq);
    float4 r3 = *((const float4*)BsP + (3 * TA + a) * 64 + pqq);
    float4 sum = make_float4((r0.x + r1.x) + (r2.x + r3.x),
                             (r0.y + r1.y) + (r2.y + r3.y),
                             (r0.z + r1.z) + (r2.z + r3.z),
                             (r0.w + r1.w) + (r2.w + r3.w));
    *((float4*)AsP + a * 64 + pqq) = sum;
  }
  __syncthreads();

  // feat: wave w = atom slot w
  int w = t >> 6, lane = t & 63;
  if (w < nrows) {
    float4 p = *((const float4*)AsP + w * 64 + lane);
    const float* bb = bias + (size_t)s * F_DIM;
    float accum = 0.f;
    for (int j = 0; j < NSTACKS; ++j) {
      unsigned sw = sgnL[j * 64 + lane];
      float4 bi = *((const float4*)(bb + j * P_DIM) + lane);
      float4 al = *((const float4*)(alpha + j * P_DIM) + lane);
      float x0 = __int_as_float(__float_as_int(p.x) ^ ((sw & 1u) << 31));
      float x1 = __int_as_float(__float_as_int(p.y) ^ ((sw & 2u) << 30));
      float x2 = __int_as_float(__float_as_int(p.z) ^ ((sw & 4u) << 29));
      float x3 = __int_as_float(__float_as_int(p.w) ^ ((sw & 8u) << 28));
      // FWHT bits 0,1 in-register
      float t0 = x0 + x1, t1 = x0 - x1, t2 = x2 + x3, t3 = x2 - x3;
      x0 = t0 + t2; x2 = t0 - t2; x1 = t1 + t3; x3 = t1 - t3;
      // FWHT bits 2..7 cross-lane
#pragma unroll
      for (int hl = 1; hl <= 32; hl <<= 1) {
        float sg = (lane & hl) ? -1.f : 1.f;
        float y0 = __shfl_xor(x0, hl);
        float y1 = __shfl_xor(x1, hl);
        float y2 = __shfl_xor(x2, hl);
        float y3 = __shfl_xor(x3, hl);
        x0 = fmaf(sg, x0, y0);
        x1 = fmaf(sg, x1, y1);
        x2 = fmaf(sg, x2, y2);
        x3 = fmaf(sg, x3, y3);
      }
      // fwht norm 1/16; COEFF_NORM = 1.0 exactly
      accum += __cosf(fmaf(x0, 0.0625f, bi.x)) * al.x;
      accum += __cosf(fmaf(x1, 0.0625f, bi.y)) * al.y;
      accum += __cosf(fmaf(x2, 0.0625f, bi.z)) * al.z;
      accum += __cosf(fmaf(x3, 0.0625f, bi.w)) * al.w;
    }
#pragma unroll
    for (int off = 1; off < 64; off <<= 1) accum += __shfl_xor(accum, off);
    if (lane == 0) {
      // FEAT_NORM = 1/64 exactly
      atomicAdd(out + (rows[w] >> 6), 0.015625f * accum);
    }
  }
}

extern "C" void kernel_launch(void* const* d_in, const int* in_sizes, int n_in,
                              void* d_out, int out_size, void* d_ws, size_t ws_size,
                              hipStream_t stream) {
  const float* rep       = (const float*)d_in[0];
  const int*   charges   = (const int*)d_in[1];
  const float* reductors = (const float*)d_in[2];
  const float* Dmat      = (const float*)d_in[3];
  const float* bias      = (const float*)d_in[4];
  const float* alpha     = (const float*)d_in[5];
  float* out = (float*)d_out;

  char* ws = (char*)d_ws;
  int*      order = (int*)ws;
  int*      meta  = (int*)(ws + 8192);
  unsigned* sgn   = (unsigned*)(ws + 16384);

  sorf_prep_kernel<<<1, 256, 0, stream>>>(charges, Dmat, order, meta, sgn, out);
  sorf_fused_kernel<<<S_DIM * 256, 512, 0, stream>>>(rep, reductors, bias, alpha,
                                                     order, meta, sgn, out);
}

// Round 4
// 117.690 us; speedup vs baseline: 2.2930x; 1.1203x over previous
//
#include <hip/hip_runtime.h>

#define NATOMS 2048
#define R_DIM 512
#define P_DIM 256
#define S_DIM 4
#define NSTACKS 32
#define F_DIM 8192
#define KS 4                 // K splits
#define KSPAN (R_DIM / KS)   // 128
#define TR 64
#define TC 64
#define KT 16

// ws layout:
//   [0, 8192)      : order  (int[2048])
//   [8192, 8224)   : meta   (gstart[4], gcount[4])
//   [16384, +8MB)  : projp  float[KS][2048][256]

__global__ __launch_bounds__(256) void sorf_prep_kernel(
    const int* __restrict__ charges, int* __restrict__ order, int* __restrict__ meta,
    float* __restrict__ out) {
  __shared__ int cnt[S_DIM];
  __shared__ int base[S_DIM];
  int t = threadIdx.x;
  if (t < 32) out[t] = 0.f;   // d_out re-poisoned before every launch
  if (t < S_DIM) cnt[t] = 0;
  __syncthreads();
  for (int i = t; i < NATOMS; i += 256) atomicAdd(&cnt[charges[i]], 1);
  __syncthreads();
  if (t == 0) {
    int run = 0;
    for (int s = 0; s < S_DIM; ++s) {
      base[s] = run; meta[s] = run; meta[4 + s] = cnt[s]; run += cnt[s];
    }
  }
  __syncthreads();
  for (int i = t; i < NATOMS; i += 256) {
    int s = charges[i];
    order[atomicAdd(&base[s], 1)] = i;
  }
}

// grid: bid -> ks(4) | cb(4) | rt(32) | s(4) = 2048 blocks, 256 threads.
// ~3/4 of row tiles are empty for a given s and return immediately.
__global__ __launch_bounds__(256) void sorf_proj_kernel(
    const float* __restrict__ rep, const float* __restrict__ reductors,
    const int* __restrict__ order, const int* __restrict__ meta,
    float* __restrict__ projp) {
  int bid = blockIdx.x;
  int ks = bid & 3;
  int cb = (bid >> 2) & 3;
  int rt = (bid >> 4) & 31;
  int s  = bid >> 9;
  int cnt = meta[4 + s];
  if (rt * TR >= cnt) return;
  int start = meta[s] + rt * TR;
  int nrows = min(TR, cnt - rt * TR);

  __shared__ int rows[TR];
  __shared__ float As[KT][TR + 4];  // stride 68: 16B-aligned rows, <=2-way bank aliasing (free)
  __shared__ float Bs[KT][TC];

  int t = threadIdx.x;
  if (t < TR) rows[t] = order[start + min(t, nrows - 1)];
  __syncthreads();

  int ar = t >> 2;        // A row staged by this thread
  int aq = t & 3;         // k-quad within KT chunk
  const float* aSrc = rep + (size_t)rows[ar] * R_DIM + ks * KSPAN + aq * 4;
  int kb = t >> 4;        // B k row
  int cc = (t & 15) * 4;  // B col quad
  const float* bSrc = reductors + ((size_t)s * R_DIM + ks * KSPAN + kb) * P_DIM + cb * TC + cc;

  int ty = t >> 4, tx = t & 15;
  int r0 = ty * 4, c0 = tx * 4;

  float acc[4][4];
#pragma unroll
  for (int i = 0; i < 4; ++i)
#pragma unroll
    for (int j = 0; j < 4; ++j) acc[i][j] = 0.f;

  float4 a = *(const float4*)aSrc;
  float4 b = *(const float4*)bSrc;

#pragma unroll 1
  for (int k0 = 0; k0 < KSPAN; k0 += KT) {
    __syncthreads();   // previous iteration's LDS reads complete
    As[aq * 4 + 0][ar] = a.x;
    As[aq * 4 + 1][ar] = a.y;
    As[aq * 4 + 2][ar] = a.z;
    As[aq * 4 + 3][ar] = a.w;
    *(float4*)&Bs[kb][cc] = b;
    __syncthreads();
    if (k0 + KT < KSPAN) {   // prefetch next chunk; latency overlaps compute below
      a = *(const float4*)(aSrc + k0 + KT);
      b = *(const float4*)(bSrc + (size_t)(k0 + KT) * P_DIM);
    }
#pragma unroll
    for (int kk = 0; kk < KT; ++kk) {
      float4 aV = *(const float4*)&As[kk][r0];
      float4 bV = *(const float4*)&Bs[kk][c0];
      float av[4] = {aV.x, aV.y, aV.z, aV.w};
      float bv[4] = {bV.x, bV.y, bV.z, bV.w};
#pragma unroll
      for (int i = 0; i < 4; ++i)
#pragma unroll
        for (int j = 0; j < 4; ++j) acc[i][j] = fmaf(av[i], bv[j], acc[i][j]);
    }
  }

  // full-line coalesced: 16 threads (tx) cover 256B of one (ks,atom) row segment
#pragma unroll
  for (int i = 0; i < 4; ++i) {
    int r = r0 + i;
    if (r < nrows) {
      float* dst = projp + ((size_t)ks * NATOMS + rows[r]) * P_DIM + cb * TC + c0;
      *(float4*)dst = make_float4(acc[i][0], acc[i][1], acc[i][2], acc[i][3]);
    }
  }
}

// grid: one block per atom; wave w handles stacks [w*8, w*8+8)
__global__ __launch_bounds__(256) void sorf_feat_kernel(
    const float* __restrict__ projp, const int* __restrict__ charges,
    const float* __restrict__ Dmat, const float* __restrict__ bias,
    const float* __restrict__ alpha, float* __restrict__ out) {
  const int atom = blockIdx.x;
  const int t = threadIdx.x;
  const int lane = t & 63;
  const int wave = t >> 6;
  const int s = charges[atom];

  // lane holds p = 4*lane+k; reduce the KS K-split partials in-register
  float4 p0 = *((const float4*)(projp + (size_t)atom * P_DIM) + lane);
  float4 p1 = *((const float4*)(projp + ((size_t)1 * NATOMS + atom) * P_DIM) + lane);
  float4 p2 = *((const float4*)(projp + ((size_t)2 * NATOMS + atom) * P_DIM) + lane);
  float4 p3 = *((const float4*)(projp + ((size_t)3 * NATOMS + atom) * P_DIM) + lane);
  float4 p = make_float4((p0.x + p1.x) + (p2.x + p3.x),
                         (p0.y + p1.y) + (p2.y + p3.y),
                         (p0.z + p1.z) + (p2.z + p3.z),
                         (p0.w + p1.w) + (p2.w + p3.w));

  const float* Db = Dmat + (size_t)s * (NSTACKS * P_DIM);
  const float* bb = bias + (size_t)s * F_DIM;
  float accum = 0.f;

#pragma unroll 2
  for (int j = wave * 8; j < wave * 8 + 8; ++j) {
    float4 d  = *((const float4*)(Db + j * P_DIM) + lane);
    float4 bi = *((const float4*)(bb + j * P_DIM) + lane);
    float4 al = *((const float4*)(alpha + j * P_DIM) + lane);
    float x0 = (d.x >= 0.f) ? p.x : -p.x;
    float x1 = (d.y >= 0.f) ? p.y : -p.y;
    float x2 = (d.z >= 0.f) ? p.z : -p.z;
    float x3 = (d.w >= 0.f) ? p.w : -p.w;
    // FWHT bits 0,1 in-register
    float t0 = x0 + x1, t1 = x0 - x1, t2 = x2 + x3, t3 = x2 - x3;
    x0 = t0 + t2; x2 = t0 - t2; x1 = t1 + t3; x3 = t1 - t3;
    // FWHT bits 2..7 via cross-lane butterflies
#pragma unroll
    for (int hl = 1; hl <= 32; hl <<= 1) {
      float sg = (lane & hl) ? -1.f : 1.f;
      float y0 = __shfl_xor(x0, hl);
      float y1 = __shfl_xor(x1, hl);
      float y2 = __shfl_xor(x2, hl);
      float y3 = __shfl_xor(x3, hl);
      x0 = fmaf(sg, x0, y0);
      x1 = fmaf(sg, x1, y1);
      x2 = fmaf(sg, x2, y2);
      x3 = fmaf(sg, x3, y3);
    }
    // fwht norm 1/16; COEFF_NORM = 1.0 exactly
    accum += __cosf(fmaf(x0, 0.0625f, bi.x)) * al.x;
    accum += __cosf(fmaf(x1, 0.0625f, bi.y)) * al.y;
    accum += __cosf(fmaf(x2, 0.0625f, bi.z)) * al.z;
    accum += __cosf(fmaf(x3, 0.0625f, bi.w)) * al.w;
  }

#pragma unroll
  for (int off = 1; off < 64; off <<= 1) accum += __shfl_xor(accum, off);
  __shared__ float wsum[4];
  if (lane == 0) wsum[wave] = accum;
  __syncthreads();
  if (t == 0) {
    // FEAT_NORM = 1/64 exactly
    atomicAdd(out + (atom >> 6), 0.015625f * ((wsum[0] + wsum[1]) + (wsum[2] + wsum[3])));
  }
}

extern "C" void kernel_launch(void* const* d_in, const int* in_sizes, int n_in,
                              void* d_out, int out_size, void* d_ws, size_t ws_size,
                              hipStream_t stream) {
  const float* rep       = (const float*)d_in[0];
  const int*   charges   = (const int*)d_in[1];
  const float* reductors = (const float*)d_in[2];
  const float* Dmat      = (const float*)d_in[3];
  const float* bias      = (const float*)d_in[4];
  const float* alpha     = (const float*)d_in[5];
  float* out = (float*)d_out;

  char* ws = (char*)d_ws;
  int*   order = (int*)ws;
  int*   meta  = (int*)(ws + 8192);
  float* projp = (float*)(ws + 16384);

  sorf_prep_kernel<<<1, 256, 0, stream>>>(charges, order, meta, out);
  sorf_proj_kernel<<<2048, 256, 0, stream>>>(rep, reductors, order, meta, projp);
  sorf_feat_kernel<<<NATOMS, 256, 0, stream>>>(projp, charges, Dmat, bias, alpha, out);
}

// Round 6
// 114.896 us; speedup vs baseline: 2.3488x; 1.0243x over previous
//
#include <hip/hip_runtime.h>

#define NATOMS 2048
#define R_DIM 512
#define P_DIM 256
#define S_DIM 4
#define NSTACKS 32
#define F_DIM 8192
#define KS 8                 // K splits
#define KSPAN (R_DIM / KS)   // 64
#define TR 64
#define TC 64
#define KT 16

// DPP lane-permute as a VALU op. Direction-proof controls only:
//   0xB1 quad_perm[1,0,3,2] = xor1 ; 0x4E quad_perm[2,3,0,1] = xor2 ;
//   0x128 row_ror:8 = xor8 (8+8=16: direction-immune) ;
//   0x124 row_ror:4 (used only in sum-reduce where direction is irrelevant)
// NEVER place DPP behind divergent control flow (incl. ternaries around calls).
#define DPPF(x, ctrl) \
  __int_as_float(__builtin_amdgcn_update_dpp( \
      __float_as_int(x), __float_as_int(x), (ctrl), 0xF, 0xF, false))

// ws layout:
//   [0, 8192)      : order  (int[2048])
//   [8192, 8224)   : meta   (gstart[4], gcount[4])
//   [16384, +16MB) : projp  float[KS][2048][256]

__global__ __launch_bounds__(256) void sorf_prep_kernel(
    const int* __restrict__ charges, int* __restrict__ order, int* __restrict__ meta,
    float* __restrict__ out) {
  __shared__ int cnt[S_DIM];
  __shared__ int base[S_DIM];
  int t = threadIdx.x;
  if (t < 32) out[t] = 0.f;   // d_out re-poisoned before every launch
  if (t < S_DIM) cnt[t] = 0;
  __syncthreads();
  for (int i = t; i < NATOMS; i += 256) atomicAdd(&cnt[charges[i]], 1);
  __syncthreads();
  if (t == 0) {
    int run = 0;
    for (int s = 0; s < S_DIM; ++s) {
      base[s] = run; meta[s] = run; meta[4 + s] = cnt[s]; run += cnt[s];
    }
  }
  __syncthreads();
  for (int i = t; i < NATOMS; i += 256) {
    int s = charges[i];
    order[atomicAdd(&base[s], 1)] = i;
  }
}

// grid: bid -> ks(8) | cb(4) | rt(32) | s(4) = 4096 blocks, 256 threads.
// ~3/4 of row tiles are empty for a given s and return immediately.
__global__ __launch_bounds__(256) void sorf_proj_kernel(
    const float* __restrict__ rep, const float* __restrict__ reductors,
    const int* __restrict__ order, const int* __restrict__ meta,
    float* __restrict__ projp) {
  int bid = blockIdx.x;
  int ks = bid & 7;
  int cb = (bid >> 3) & 3;
  int rt = (bid >> 5) & 31;
  int s  = bid >> 10;
  int cnt = meta[4 + s];
  if (rt * TR >= cnt) return;
  int start = meta[s] + rt * TR;
  int nrows = min(TR, cnt - rt * TR);

  __shared__ int rows[TR];
  __shared__ float As[KT][TR + 4];  // stride 68: 16B-aligned rows, <=2-way bank aliasing (free)
  __shared__ float Bs[KT][TC];

  int t = threadIdx.x;
  if (t < TR) rows[t] = order[start + min(t, nrows - 1)];
  __syncthreads();

  int ar = t >> 2;        // A row staged by this thread
  int aq = t & 3;         // k-quad within KT chunk
  const float* aSrc = rep + (size_t)rows[ar] * R_DIM + ks * KSPAN + aq * 4;
  int kb = t >> 4;        // B k row
  int cc = (t & 15) * 4;  // B col quad
  const float* bSrc = reductors + ((size_t)s * R_DIM + ks * KSPAN + kb) * P_DIM + cb * TC + cc;

  int ty = t >> 4, tx = t & 15;
  int r0 = ty * 4, c0q = tx * 4;

  float acc[4][4];
#pragma unroll
  for (int i = 0; i < 4; ++i)
#pragma unroll
    for (int j = 0; j < 4; ++j) acc[i][j] = 0.f;

  float4 a = *(const float4*)aSrc;
  float4 b = *(const float4*)bSrc;

#pragma unroll 1
  for (int k0 = 0; k0 < KSPAN; k0 += KT) {
    __syncthreads();   // previous iteration's LDS reads complete
    As[aq * 4 + 0][ar] = a.x;
    As[aq * 4 + 1][ar] = a.y;
    As[aq * 4 + 2][ar] = a.z;
    As[aq * 4 + 3][ar] = a.w;
    *(float4*)&Bs[kb][cc] = b;
    __syncthreads();
    if (k0 + KT < KSPAN) {   // prefetch next chunk; latency overlaps compute below
      a = *(const float4*)(aSrc + k0 + KT);
      b = *(const float4*)(bSrc + (size_t)(k0 + KT) * P_DIM);
    }
#pragma unroll
    for (int kk = 0; kk < KT; ++kk) {
      float4 aV = *(const float4*)&As[kk][r0];
      float4 bV = *(const float4*)&Bs[kk][c0q];
      float av[4] = {aV.x, aV.y, aV.z, aV.w};
      float bv[4] = {bV.x, bV.y, bV.z, bV.w};
#pragma unroll
      for (int i = 0; i < 4; ++i)
#pragma unroll
        for (int j = 0; j < 4; ++j) acc[i][j] = fmaf(av[i], bv[j], acc[i][j]);
    }
  }

  // full-line coalesced: 16 threads (tx) cover 256B of one (ks,atom) row segment
#pragma unroll
  for (int i = 0; i < 4; ++i) {
    int r = r0 + i;
    if (r < nrows) {
      float* dst = projp + ((size_t)ks * NATOMS + rows[r]) * P_DIM + cb * TC + c0q;
      *(float4*)dst = make_float4(acc[i][0], acc[i][1], acc[i][2], acc[i][3]);
    }
  }
}

// grid: one block per atom; wave w handles stacks [w*8, w*8+8)
__global__ __launch_bounds__(256) void sorf_feat_kernel(
    const float* __restrict__ projp, const int* __restrict__ charges,
    const float* __restrict__ Dmat, const float* __restrict__ bias,
    const float* __restrict__ alpha, float* __restrict__ out) {
  const int atom = blockIdx.x;
  const int t = threadIdx.x;
  const int lane = t & 63;
  const int wave = t >> 6;
  const int s = charges[atom];

  // lane holds p = 4*lane+k; reduce the KS K-split partials in-register
  float4 p = *((const float4*)(projp + (size_t)atom * P_DIM) + lane);
#pragma unroll
  for (int ksi = 1; ksi < KS; ++ksi) {
    float4 q = *((const float4*)(projp + ((size_t)ksi * NATOMS + atom) * P_DIM) + lane);
    p.x += q.x; p.y += q.y; p.z += q.z; p.w += q.w;
  }

  const float sg1  = (lane & 1)  ? -1.f : 1.f;
  const float sg2  = (lane & 2)  ? -1.f : 1.f;
  const float sg4  = (lane & 4)  ? -1.f : 1.f;
  const float sg8  = (lane & 8)  ? -1.f : 1.f;
  const float sg16 = (lane & 16) ? -1.f : 1.f;
  const float sg32 = (lane & 32) ? -1.f : 1.f;

  const float* Db = Dmat + (size_t)s * (NSTACKS * P_DIM);
  const float* bb = bias + (size_t)s * F_DIM;
  float accum = 0.f;

#pragma unroll 2
  for (int j = wave * 8; j < wave * 8 + 8; ++j) {
    float4 d  = *((const float4*)(Db + j * P_DIM) + lane);
    float4 bi = *((const float4*)(bb + j * P_DIM) + lane);
    float4 al = *((const float4*)(alpha + j * P_DIM) + lane);
    float x0 = (d.x >= 0.f) ? p.x : -p.x;
    float x1 = (d.y >= 0.f) ? p.y : -p.y;
    float x2 = (d.z >= 0.f) ? p.z : -p.z;
    float x3 = (d.w >= 0.f) ? p.w : -p.w;
    // FWHT bits 0,1 in-register
    float t0 = x0 + x1, t1 = x0 - x1, t2 = x2 + x3, t3 = x2 - x3;
    x0 = t0 + t2; x2 = t0 - t2; x1 = t1 + t3; x3 = t1 - t3;
    // stage xor1 (DPP quad_perm [1,0,3,2] — explicit permutation, direction-proof)
    { float y0 = DPPF(x0, 0xB1), y1 = DPPF(x1, 0xB1), y2 = DPPF(x2, 0xB1), y3 = DPPF(x3, 0xB1);
      x0 = fmaf(sg1, x0, y0); x1 = fmaf(sg1, x1, y1);
      x2 = fmaf(sg1, x2, y2); x3 = fmaf(sg1, x3, y3); }
    // stage xor2 (DPP quad_perm [2,3,0,1])
    { float y0 = DPPF(x0, 0x4E), y1 = DPPF(x1, 0x4E), y2 = DPPF(x2, 0x4E), y3 = DPPF(x3, 0x4E);
      x0 = fmaf(sg2, x0, y0); x1 = fmaf(sg2, x1, y1);
      x2 = fmaf(sg2, x2, y2); x3 = fmaf(sg2, x3, y3); }
    // stage xor4 (shfl — DS pipe; row_shl/shr direction burned us in R5)
    { float y0 = __shfl_xor(x0, 4), y1 = __shfl_xor(x1, 4),
            y2 = __shfl_xor(x2, 4), y3 = __shfl_xor(x3, 4);
      x0 = fmaf(sg4, x0, y0); x1 = fmaf(sg4, x1, y1);
      x2 = fmaf(sg4, x2, y2); x3 = fmaf(sg4, x3, y3); }
    // stage xor8 (DPP row_ror:8 — 8+8=16, direction-immune)
    { float y0 = DPPF(x0, 0x128), y1 = DPPF(x1, 0x128), y2 = DPPF(x2, 0x128), y3 = DPPF(x3, 0x128);
      x0 = fmaf(sg8, x0, y0); x1 = fmaf(sg8, x1, y1);
      x2 = fmaf(sg8, x2, y2); x3 = fmaf(sg8, x3, y3); }
    // stage xor16 (shfl)
    { float y0 = __shfl_xor(x0, 16), y1 = __shfl_xor(x1, 16),
            y2 = __shfl_xor(x2, 16), y3 = __shfl_xor(x3, 16);
      x0 = fmaf(sg16, x0, y0); x1 = fmaf(sg16, x1, y1);
      x2 = fmaf(sg16, x2, y2); x3 = fmaf(sg16, x3, y3); }
    // stage xor32 (shfl)
    { float y0 = __shfl_xor(x0, 32), y1 = __shfl_xor(x1, 32),
            y2 = __shfl_xor(x2, 32), y3 = __shfl_xor(x3, 32);
      x0 = fmaf(sg32, x0, y0); x1 = fmaf(sg32, x1, y1);
      x2 = fmaf(sg32, x2, y2); x3 = fmaf(sg32, x3, y3); }
    // fwht norm 1/16; COEFF_NORM = 1.0 exactly
    accum += __cosf(fmaf(x0, 0.0625f, bi.x)) * al.x;
    accum += __cosf(fmaf(x1, 0.0625f, bi.y)) * al.y;
    accum += __cosf(fmaf(x2, 0.0625f, bi.z)) * al.z;
    accum += __cosf(fmaf(x3, 0.0625f, bi.w)) * al.w;
  }

  // wave sum-reduce: permutation-invariant, so ror direction is irrelevant.
  // quad stages -> quad sums; ror:4 + ror:8 accumulate all 4 quads of each
  // 16-row; shfl 16/32 finish across rows.
  accum += DPPF(accum, 0xB1);
  accum += DPPF(accum, 0x4E);
  accum += DPPF(accum, 0x124);   // row_ror:4
  accum += DPPF(accum, 0x128);   // row_ror:8
  accum += __shfl_xor(accum, 16);
  accum += __shfl_xor(accum, 32);

  __shared__ float wsum[4];
  if (lane == 0) wsum[wave] = accum;
  __syncthreads();
  if (t == 0) {
    // FEAT_NORM = 1/64 exactly
    atomicAdd(out + (atom >> 6), 0.015625f * ((wsum[0] + wsum[1]) + (wsum[2] + wsum[3])));
  }
}

extern "C" void kernel_launch(void* const* d_in, const int* in_sizes, int n_in,
                              void* d_out, int out_size, void* d_ws, size_t ws_size,
                              hipStream_t stream) {
  const float* rep       = (const float*)d_in[0];
  const int*   charges   = (const int*)d_in[1];
  const float* reductors = (const float*)d_in[2];
  const float* Dmat      = (const float*)d_in[3];
  const float* bias      = (const float*)d_in[4];
  const float* alpha     = (const float*)d_in[5];
  float* out = (float*)d_out;

  char* ws = (char*)d_ws;
  int*   order = (int*)ws;
  int*   meta  = (int*)(ws + 8192);
  float* projp = (float*)(ws + 16384);

  sorf_prep_kernel<<<1, 256, 0, stream>>>(charges, order, meta, out);
  sorf_proj_kernel<<<8 * 4 * 32 * S_DIM, 256, 0, stream>>>(rep, reductors, order, meta, projp);
  sorf_feat_kernel<<<NATOMS, 256, 0, stream>>>(projp, charges, Dmat, bias, alpha, out);
}

// Round 7
// 111.671 us; speedup vs baseline: 2.4166x; 1.0289x over previous
//
#include <hip/hip_runtime.h>

#define NATOMS 2048
#define R_DIM 512
#define P_DIM 256
#define S_DIM 4
#define NSTACKS 32
#define F_DIM 8192
#define KS 8                 // K splits
#define KSPAN (R_DIM / KS)   // 64
#define TR 64                // atoms per tile
#define TC 128               // cols per tile
#define KT 16                // k chunk
#define RT_TILES 11          // covers cnt_s up to 704 (mean 512, sd 19.4 — 9.9 sigma)

// DPP lane-permute as a VALU op (1 instr, no DS pipe).
//   0xB1 quad_perm[1,0,3,2] = xor1          (validated R6)
//   0x4E quad_perm[2,3,0,1] = xor2          (validated R6)
//   0x128 row_ror:8 = xor8 within 16-rows   (validated R6)
//   0x124 row_ror:4 (sum-reduce only)       (validated R6)
//   0x104 row_shl:4 -> lane i gets i+4 ; 0x114 row_shr:4 -> lane i gets i-4
//   (direction per the canonical DPP prefix-sum idiom: row_shr:1 feeds lane i
//    from lane i-1). xor4 = select shl-result on bit2=0 lanes, shr on bit2=1.
// NEVER put DPP calls inside conditional expressions — compute both, cndmask.
#define DPPF(x, ctrl) \
  __int_as_float(__builtin_amdgcn_update_dpp( \
      __float_as_int(x), __float_as_int(x), (ctrl), 0xF, 0xF, false))

// ws layout: [16384, +16MB) : projp float[KS][2048][256]

// grid: bid = ks(8) | cb(1bit) | (rt,s): 8*2*11*4 = 704 blocks, 256 threads.
__global__ __launch_bounds__(256) void sorf_proj_kernel(
    const float* __restrict__ rep, const float* __restrict__ reductors,
    const int* __restrict__ charges, float* __restrict__ projp,
    float* __restrict__ out) {
  int bid = blockIdx.x;
  int ks = bid & 7;
  int cb = (bid >> 3) & 1;
  int r2 = bid >> 4;            // 0..43
  int rt = r2 % RT_TILES;
  int s  = r2 / RT_TILES;

  int t = threadIdx.x;
  int lane = t & 63, wave = t >> 6;
  if (bid == 0 && t < 32) out[t] = 0.f;  // before any exit; d_out re-poisoned each launch

  // ---- in-block charge scan: row list for this (s, rt) tile ----
  // thread t owns atoms 8t..8t+7 (ascending thread order == atom order).
  __shared__ int rowsL[TR];
  __shared__ int wtot[4];
  int4 c0v = ((const int4*)charges)[t * 2];
  int4 c1v = ((const int4*)charges)[t * 2 + 1];
  int fl[8];
  fl[0] = (c0v.x == s); fl[1] = (c0v.y == s); fl[2] = (c0v.z == s); fl[3] = (c0v.w == s);
  fl[4] = (c1v.x == s); fl[5] = (c1v.y == s); fl[6] = (c1v.z == s); fl[7] = (c1v.w == s);
  int cnt8 = ((fl[0] + fl[1]) + (fl[2] + fl[3])) + ((fl[4] + fl[5]) + (fl[6] + fl[7]));
  int scan = cnt8;                       // inclusive scan over lanes
#pragma unroll
  for (int o = 1; o < 64; o <<= 1) {
    int y = __shfl_up(scan, o);
    if (lane >= o) scan += y;
  }
  if (lane == 63) wtot[wave] = scan;
  __syncthreads();
  int wb = 0;
#pragma unroll
  for (int w = 0; w < 4; ++w) wb += (w < wave) ? wtot[w] : 0;
  int total = (wtot[0] + wtot[1]) + (wtot[2] + wtot[3]);
  int lo = rt * TR;
  int nrows = min(TR, total - lo);       // uniform across block
  if (nrows <= 0) return;
  if (t >= nrows && t < TR) rowsL[t] = 0;  // dummy rows for staging reads (stores guarded)
  int pos = wb + scan - cnt8;            // exclusive prefix = rank of this thread's 1st match
#pragma unroll
  for (int i = 0; i < 8; ++i) {
    if (fl[i]) {
      int rel = pos - lo;
      if (rel >= 0 && rel < TR) rowsL[rel] = t * 8 + i;
      pos++;
    }
  }
  __syncthreads();

  // ---- 64 x 128 tile GEMM over this ks K-slice (4x8 register tile) ----
  __shared__ float As[KT][TR + 4];   // stride 68: 16B-aligned rows, 2-way aliasing (free)
  __shared__ float Bs[KT][TC];       // quads read at tx*4 and 64+tx*4: 2-way (free)

  int ar = t >> 2;        // A row staged by this thread
  int aq = t & 3;         // k-quad within KT chunk
  const float* aSrc = rep + (size_t)rowsL[ar] * R_DIM + ks * KSPAN + aq * 4;
  int kb = t >> 4;        // B k row
  int cc = (t & 15) * 4;  // B col quad (plus +64 partner)
  const float* bSrc = reductors + ((size_t)s * R_DIM + ks * KSPAN + kb) * P_DIM + cb * TC + cc;

  int ty = t >> 4, tx = t & 15;
  int r0 = ty * 4;
  int c0 = tx * 4;        // cols c0..c0+3 and c0+64..c0+67

  float acc[4][8];
#pragma unroll
  for (int i = 0; i < 4; ++i)
#pragma unroll
    for (int j = 0; j < 8; ++j) acc[i][j] = 0.f;

  float4 a  = *(const float4*)aSrc;
  float4 b0 = *(const float4*)bSrc;
  float4 b1 = *(const float4*)(bSrc + 64);

#pragma unroll 1
  for (int k0 = 0; k0 < KSPAN; k0 += KT) {
    __syncthreads();   // previous iteration's LDS reads complete
    As[aq * 4 + 0][ar] = a.x;
    As[aq * 4 + 1][ar] = a.y;
    As[aq * 4 + 2][ar] = a.z;
    As[aq * 4 + 3][ar] = a.w;
    *(float4*)&Bs[kb][cc] = b0;
    *(float4*)&Bs[kb][cc + 64] = b1;
    __syncthreads();
    if (k0 + KT < KSPAN) {   // prefetch next chunk; latency overlaps compute below
      a  = *(const float4*)(aSrc + k0 + KT);
      b0 = *(const float4*)(bSrc + (size_t)(k0 + KT) * P_DIM);
      b1 = *(const float4*)(bSrc + (size_t)(k0 + KT) * P_DIM + 64);
    }
#pragma unroll
    for (int kk = 0; kk < KT; ++kk) {
      float4 aV = *(const float4*)&As[kk][r0];
      float4 bA = *(const float4*)&Bs[kk][c0];
      float4 bB = *(const float4*)&Bs[kk][c0 + 64];
      float av[4] = {aV.x, aV.y, aV.z, aV.w};
      float bv[8] = {bA.x, bA.y, bA.z, bA.w, bB.x, bB.y, bB.z, bB.w};
#pragma unroll
      for (int i = 0; i < 4; ++i)
#pragma unroll
        for (int j = 0; j < 8; ++j) acc[i][j] = fmaf(av[i], bv[j], acc[i][j]);
    }
  }

  // coalesced: 16 threads (tx) cover each 256B half-row segment
#pragma unroll
  for (int i = 0; i < 4; ++i) {
    int r = r0 + i;
    if (r < nrows) {
      float* dst = projp + ((size_t)ks * NATOMS + rowsL[r]) * P_DIM + cb * TC + c0;
      *(float4*)dst = make_float4(acc[i][0], acc[i][1], acc[i][2], acc[i][3]);
      *(float4*)(dst + 64) = make_float4(acc[i][4], acc[i][5], acc[i][6], acc[i][7]);
    }
  }
}

// grid: one block per atom; wave w handles stacks [w*8, w*8+8)
__global__ __launch_bounds__(256) void sorf_feat_kernel(
    const float* __restrict__ projp, const int* __restrict__ charges,
    const float* __restrict__ Dmat, const float* __restrict__ bias,
    const float* __restrict__ alpha, float* __restrict__ out) {
  const int atom = blockIdx.x;
  const int t = threadIdx.x;
  const int lane = t & 63;
  const int wave = t >> 6;
  const int s = charges[atom];

  // lane holds p = 4*lane+k; reduce the KS K-split partials in-register
  float4 p = *((const float4*)(projp + (size_t)atom * P_DIM) + lane);
#pragma unroll
  for (int ksi = 1; ksi < KS; ++ksi) {
    float4 q = *((const float4*)(projp + ((size_t)ksi * NATOMS + atom) * P_DIM) + lane);
    p.x += q.x; p.y += q.y; p.z += q.z; p.w += q.w;
  }

  const float sg1  = (lane & 1)  ? -1.f : 1.f;
  const float sg2  = (lane & 2)  ? -1.f : 1.f;
  const float sg4  = (lane & 4)  ? -1.f : 1.f;
  const float sg8  = (lane & 8)  ? -1.f : 1.f;
  const float sg16 = (lane & 16) ? -1.f : 1.f;
  const float sg32 = (lane & 32) ? -1.f : 1.f;
  const bool hi4 = (lane & 4) != 0;

  const float* Db = Dmat + (size_t)s * (NSTACKS * P_DIM);
  const float* bb = bias + (size_t)s * F_DIM;
  float accum = 0.f;

#pragma unroll 2
  for (int j = wave * 8; j < wave * 8 + 8; ++j) {
    float4 d  = *((const float4*)(Db + j * P_DIM) + lane);
    float4 bi = *((const float4*)(bb + j * P_DIM) + lane);
    float4 al = *((const float4*)(alpha + j * P_DIM) + lane);
    float x0 = (d.x >= 0.f) ? p.x : -p.x;
    float x1 = (d.y >= 0.f) ? p.y : -p.y;
    float x2 = (d.z >= 0.f) ? p.z : -p.z;
    float x3 = (d.w >= 0.f) ? p.w : -p.w;
    // FWHT bits 0,1 in-register
    float t0 = x0 + x1, t1 = x0 - x1, t2 = x2 + x3, t3 = x2 - x3;
    x0 = t0 + t2; x2 = t0 - t2; x1 = t1 + t3; x3 = t1 - t3;
    // stage xor1 (DPP quad_perm)
    { float y0 = DPPF(x0, 0xB1), y1 = DPPF(x1, 0xB1), y2 = DPPF(x2, 0xB1), y3 = DPPF(x3, 0xB1);
      x0 = fmaf(sg1, x0, y0); x1 = fmaf(sg1, x1, y1);
      x2 = fmaf(sg1, x2, y2); x3 = fmaf(sg1, x3, y3); }
    // stage xor2 (DPP quad_perm)
    { float y0 = DPPF(x0, 0x4E), y1 = DPPF(x1, 0x4E), y2 = DPPF(x2, 0x4E), y3 = DPPF(x3, 0x4E);
      x0 = fmaf(sg2, x0, y0); x1 = fmaf(sg2, x1, y1);
      x2 = fmaf(sg2, x2, y2); x3 = fmaf(sg2, x3, y3); }
    // stage xor4: both DPP shifts unconditionally, branchless select.
    // bit2=0 lanes need partner i+4 (row_shl:4); bit2=1 need i-4 (row_shr:4).
    { float a0 = DPPF(x0, 0x104), a1 = DPPF(x1, 0x104), a2 = DPPF(x2, 0x104), a3 = DPPF(x3, 0x104);
      float b0 = DPPF(x0, 0x114), b1 = DPPF(x1, 0x114), b2 = DPPF(x2, 0x114), b3 = DPPF(x3, 0x114);
      float y0 = hi4 ? b0 : a0;
      float y1 = hi4 ? b1 : a1;
      float y2 = hi4 ? b2 : a2;
      float y3 = hi4 ? b3 : a3;
      x0 = fmaf(sg4, x0, y0); x1 = fmaf(sg4, x1, y1);
      x2 = fmaf(sg4, x2, y2); x3 = fmaf(sg4, x3, y3); }
    // stage xor8 (DPP row_ror:8)
    { float y0 = DPPF(x0, 0x128), y1 = DPPF(x1, 0x128), y2 = DPPF(x2, 0x128), y3 = DPPF(x3, 0x128);
      x0 = fmaf(sg8, x0, y0); x1 = fmaf(sg8, x1, y1);
      x2 = fmaf(sg8, x2, y2); x3 = fmaf(sg8, x3, y3); }
    // stage xor16 (shfl)
    { float y0 = __shfl_xor(x0, 16), y1 = __shfl_xor(x1, 16),
            y2 = __shfl_xor(x2, 16), y3 = __shfl_xor(x3, 16);
      x0 = fmaf(sg16, x0, y0); x1 = fmaf(sg16, x1, y1);
      x2 = fmaf(sg16, x2, y2); x3 = fmaf(sg16, x3, y3); }
    // stage xor32 (shfl)
    { float y0 = __shfl_xor(x0, 32), y1 = __shfl_xor(x1, 32),
            y2 = __shfl_xor(x2, 32), y3 = __shfl_xor(x3, 32);
      x0 = fmaf(sg32, x0, y0); x1 = fmaf(sg32, x1, y1);
      x2 = fmaf(sg32, x2, y2); x3 = fmaf(sg32, x3, y3); }
    // fwht norm 1/16; COEFF_NORM = 1.0 exactly
    accum += __cosf(fmaf(x0, 0.0625f, bi.x)) * al.x;
    accum += __cosf(fmaf(x1, 0.0625f, bi.y)) * al.y;
    accum += __cosf(fmaf(x2, 0.0625f, bi.z)) * al.z;
    accum += __cosf(fmaf(x3, 0.0625f, bi.w)) * al.w;
  }

  // wave sum-reduce (permutation-invariant: ror direction irrelevant)
  accum += DPPF(accum, 0xB1);
  accum += DPPF(accum, 0x4E);
  accum += DPPF(accum, 0x124);   // row_ror:4
  accum += DPPF(accum, 0x128);   // row_ror:8
  accum += __shfl_xor(accum, 16);
  accum += __shfl_xor(accum, 32);

  __shared__ float wsum[4];
  if (lane == 0) wsum[wave] = accum;
  __syncthreads();
  if (t == 0) {
    // FEAT_NORM = 1/64 exactly
    atomicAdd(out + (atom >> 6), 0.015625f * ((wsum[0] + wsum[1]) + (wsum[2] + wsum[3])));
  }
}

extern "C" void kernel_launch(void* const* d_in, const int* in_sizes, int n_in,
                              void* d_out, int out_size, void* d_ws, size_t ws_size,
                              hipStream_t stream) {
  const float* rep       = (const float*)d_in[0];
  const int*   charges   = (const int*)d_in[1];
  const float* reductors = (const float*)d_in[2];
  const float* Dmat      = (const float*)d_in[3];
  const float* bias      = (const float*)d_in[4];
  const float* alpha     = (const float*)d_in[5];
  float* out = (float*)d_out;

  float* projp = (float*)((char*)d_ws + 16384);

  sorf_proj_kernel<<<8 * 2 * RT_TILES * S_DIM, 256, 0, stream>>>(
      rep, reductors, charges, projp, out);
  sorf_feat_kernel<<<NATOMS, 256, 0, stream>>>(projp, charges, Dmat, bias, alpha, out);
}